// Round 14
// baseline (254.055 us; speedup 1.0000x reference)
//
#include <hip/hip_runtime.h>

// Problem constants (match reference setup_inputs)
static constexpr int M_ROWS = 100000;
static constexpr int N_IN   = 150000;
static constexpr int C_IN   = 32;
static constexpr int CO     = 64;
static constexpr float EPS  = 1e-5f;
static constexpr int  FCAP  = 256;   // bulk feature range capacity (rows)

typedef __bf16 bf16x8 __attribute__((ext_vector_type(8)));
typedef float  f32x4  __attribute__((ext_vector_type(4)));
typedef unsigned short u16x8 __attribute__((ext_vector_type(8)));
typedef short  short8 __attribute__((ext_vector_type(8)));
typedef unsigned int u32;

static __device__ __forceinline__ unsigned short f2bf(float f) {
    unsigned int u = __builtin_bit_cast(unsigned int, f);
    u += 0x7fff + ((u >> 16) & 1);              // round-to-nearest-even
    return (unsigned short)(u >> 16);
}
static __device__ __forceinline__ float bf2f(unsigned short h) {
    unsigned int u = ((unsigned int)h) << 16;
    return __builtin_bit_cast(float, u);
}
static __device__ __forceinline__ bf16x8 bfzero() {
    short8 z = {0,0,0,0,0,0,0,0};
    return __builtin_bit_cast(bf16x8, z);
}

// async global->LDS, 16B per lane. lds ptr must be wave-uniform.
static __device__ __forceinline__ void gload_lds16(const void* g, void* l) {
    __builtin_amdgcn_global_load_lds(
        (const __attribute__((address_space(1))) u32*)g,
        (__attribute__((address_space(3))) u32*)l, 16, 0, 0);
}

// ---------------------------------------------------------------------------
// f32 -> bf16 elementwise cast (8 elems/thread)
// ---------------------------------------------------------------------------
__global__ __launch_bounds__(256) void cvt_bf16(
    const float* __restrict__ in, unsigned short* __restrict__ out, int n8)
{
    int i = blockIdx.x * 256 + threadIdx.x;
    if (i >= n8) return;
    float4 a = ((const float4*)in)[2 * i];
    float4 b = ((const float4*)in)[2 * i + 1];
    u16x8 v;
    v[0] = f2bf(a.x); v[1] = f2bf(a.y); v[2] = f2bf(a.z); v[3] = f2bf(a.w);
    v[4] = f2bf(b.x); v[5] = f2bf(b.y); v[6] = f2bf(b.z); v[7] = f2bf(b.w);
    ((u16x8*)out)[i] = v;
}

// ---------------------------------------------------------------------------
// Weight cast + transpose + XOR-swizzle (round-4 scheme).
// ---------------------------------------------------------------------------
__global__ __launch_bounds__(256) void wt_cvt_swz(
    const float* __restrict__ W, unsigned short* __restrict__ WT, int total, int cin)
{
    int t = blockIdx.x * 256 + threadIdx.x;
    if (t >= total) return;
    int k  = t / (cin * 64);
    int r  = t - k * (cin * 64);
    int ci = r >> 6;
    int co = r & 63;
    int xm = (cin == 64) ? ((co & 7) << 4) : ((co & 3) << 4);
    int phys = co * (cin * 2) + ((ci * 2) ^ xm);
    WT[(size_t)k * cin * 64 + (phys >> 1)] = f2bf(W[t]);
}

// ---------------------------------------------------------------------------
// OLD-STYLE conv (r13 phase-resident) for down conv + proj.
// SWZIN: input feature rows are XOR-swizzled (byte^=(row&7)<<4, CIN=64).
// ---------------------------------------------------------------------------
template<int CIN, int KOFF, int PH, bool GATHER, bool OUTBF, bool SWZIN>
__global__ __launch_bounds__(256, 2) void spconv_mfma(
    const unsigned short* __restrict__ fB,
    int nZero,
    const int*   __restrict__ nbr,
    const unsigned short* __restrict__ WTs,
    void* __restrict__ outp,
    float* __restrict__ part)
{
    constexpr int KS    = CIN / 32;
    constexpr int ST    = 2;
    constexpr int SLAB  = CIN * 64;
    constexpr int P1    = (KOFF < PH) ? KOFF : PH;
    constexpr int NF    = KOFF / PH;
    constexpr int T     = KOFF - NF * PH;

    __shared__ unsigned short Wl[P1 * SLAB];
    __shared__ int nbrS[GATHER ? 128 * KOFF : 4];
    __shared__ float red[4][2][64];

    const int tid  = threadIdx.x;
    const int lane = tid & 63;
    const int wv   = tid >> 6;
    const int colb = lane & 15;
    const int kgrp = lane >> 4;

    const int nwg = gridDim.x;
    const int q   = nwg >> 3, r8 = nwg & 7;
    const int xcd = blockIdx.x & 7, pos = blockIdx.x >> 3;
    const int wg  = (xcd < r8 ? xcd * (q + 1) : r8 * (q + 1) + (xcd - r8) * q) + pos;
    const int m0  = wg * 128;

    auto stageN = [&](int k0, int cnt) {
        const unsigned short* g = WTs + (size_t)k0 * SLAB;
        const int reps = cnt * (SLAB / 2048);
        for (int r = 0; r < reps; ++r) {
            const void* gp = g + (size_t)(r * 256 + tid) * 8;
            void* lp = &Wl[(size_t)(r * 256 + wv * 64) * 8];
            gload_lds16(gp, lp);
        }
    };

    stageN(0, P1);
    if (GATHER) {
        const int* src = nbr + (size_t)m0 * KOFF;
        constexpr int TOT = 128 * KOFF;
        if (m0 + 128 <= M_ROWS) {
            #pragma unroll 1
            for (int i = tid; i < TOT / 4; i += 256)
                ((int4*)nbrS)[i] = ((const int4*)src)[i];
        } else {
            #pragma unroll 1
            for (int i = tid; i < TOT; i += 256) {
                int r = i / KOFF;
                nbrS[i] = (m0 + r < M_ROWS) ? src[i] : -1;
            }
        }
    }
    __syncthreads();

    auto gatherA = [&](int k, bf16x8 (&dst)[ST][KS]) {
        #pragma unroll
        for (int st = 0; st < ST; ++st) {
            int rloc = wv * (ST * 16) + st * 16 + colb;
            int idx;
            if (GATHER) idx = nbrS[rloc * KOFF + k];
            else        idx = (m0 + rloc < M_ROWS) ? (m0 + rloc) : -1;
            if (idx < 0) idx = nZero;
            const char* gb = (const char*)(fB + (size_t)idx * CIN);
            int xm = SWZIN ? ((idx & 7) << 4) : 0;
            #pragma unroll
            for (int s = 0; s < KS; ++s)
                dst[st][s] = *reinterpret_cast<const bf16x8*>(
                    gb + ((kgrp * 16 + s * 64) ^ xm));
        }
    };

    f32x4 acc[ST][4] = {};

    auto compute = [&](int slab, const bf16x8 (&a)[ST][KS]) {
        bf16x8 w[4][KS];
        const char* base = (const char*)&Wl[0] + (size_t)slab * SLAB * 2;
        #pragma unroll
        for (int n = 0; n < 4; ++n) {
            int r  = n * 16 + colb;
            int xm = (CIN == 64) ? ((r & 7) << 4) : ((r & 3) << 4);
            #pragma unroll
            for (int s = 0; s < KS; ++s) {
                int c2 = kgrp * 16 + s * 64;
                int phys = r * (CIN * 2) + (c2 ^ xm);
                w[n][s] = *reinterpret_cast<const bf16x8*>(base + phys);
            }
        }
        #pragma unroll
        for (int st = 0; st < ST; ++st)
            #pragma unroll
            for (int n = 0; n < 4; ++n)
                #pragma unroll
                for (int s = 0; s < KS; ++s)
                    acc[st][n] = __builtin_amdgcn_mfma_f32_16x16x32_bf16(
                        a[st][s], w[n][s], acc[st][n], 0, 0, 0);
    };

    #pragma unroll 1
    for (int p = 0; p < NF; ++p) {
        const int k0 = p * PH;
        #pragma unroll
        for (int kk = 0; kk < PH; ++kk) {
            bf16x8 a[ST][KS];
            gatherA(k0 + kk, a);
            compute(kk, a);
        }
        if (p + 1 < NF || T > 0) {
            __syncthreads();
            stageN((p + 1) * PH, (p + 1 < NF) ? PH : T);
            __syncthreads();
        }
    }
    if (T > 0) {
        #pragma unroll
        for (int kk = 0; kk < T; ++kk) {
            bf16x8 a[ST][KS];
            gatherA(NF * PH + kk, a);
            compute(kk, a);
        }
    }

    #pragma unroll
    for (int st = 0; st < ST; ++st) {
        int rbase = m0 + wv * (ST * 16) + st * 16 + kgrp * 4;
        #pragma unroll
        for (int j = 0; j < 4; ++j) {
            int row = rbase + j;
            if (row < M_ROWS) {
                if (OUTBF) {
                    unsigned short* o = (unsigned short*)outp;
                    #pragma unroll
                    for (int n = 0; n < 4; ++n)
                        o[(size_t)row * 64 + n * 16 + colb] = f2bf(acc[st][n][j]);
                } else {
                    float* o = (float*)outp;
                    #pragma unroll
                    for (int n = 0; n < 4; ++n)
                        o[(size_t)row * 64 + n * 16 + colb] = acc[st][n][j];
                }
            }
        }
    }

    float s4[4], q4[4];
    #pragma unroll
    for (int n = 0; n < 4; ++n) {
        float s = 0.f, qq = 0.f;
        #pragma unroll
        for (int st = 0; st < ST; ++st)
            #pragma unroll
            for (int j = 0; j < 4; ++j) {
                float v = acc[st][n][j];
                s += v; qq += v * v;
            }
        s4[n] = s; q4[n] = qq;
    }
    #pragma unroll
    for (int n = 0; n < 4; ++n) {
        s4[n] += __shfl_xor(s4[n], 16); s4[n] += __shfl_xor(s4[n], 32);
        q4[n] += __shfl_xor(q4[n], 16); q4[n] += __shfl_xor(q4[n], 32);
    }
    if (kgrp == 0) {
        #pragma unroll
        for (int n = 0; n < 4; ++n) {
            red[wv][0][n * 16 + colb] = s4[n];
            red[wv][1][n * 16 + colb] = q4[n];
        }
    }
    __syncthreads();
    if (tid < 64) {
        float S = red[0][0][tid] + red[1][0][tid] + red[2][0][tid] + red[3][0][tid];
        float Q = red[0][1][tid] + red[1][1][tid] + red[2][1][tid] + red[3][1][tid];
        part[(size_t)wg * 128 + tid]      = S;
        part[(size_t)wg * 128 + 64 + tid] = Q;
    }
}

// ---------------------------------------------------------------------------
// NEW: 27-tap subM conv with BULK-RANGE LDS feature staging.
// 9 (dx,dy) groups x 3 dz taps. Per group: min(idx) over block (LDS
// atomicMin), bulk-load rows [lo, lo+FCAP) with 8 coalesced global_load_lds,
// then 3 taps gather FROM LDS (features pre-XOR-swizzled globally by
// absolute row => ~conflict-free ds_read). Double-buffered feat+weights,
// 9 barriers total. Out-of-range idx -> predicated global fallback;
// idx<0 -> in-register zero. Attacks the scattered-VMEM MSHR bound that
// was invariant across r5-r13.
// ---------------------------------------------------------------------------
template<bool OUTBF>
__global__ __launch_bounds__(256) void spconv_sub27(
    const unsigned short* __restrict__ fBs,  // swizzled rows [M+1+FCAP][64]
    const int*   __restrict__ nbr,           // [M][27]
    const unsigned short* __restrict__ WTs,  // swizzled slabs [27][64][64]
    void* __restrict__ outp,
    float* __restrict__ part)
{
    constexpr int SLAB = 64 * 64;   // ushorts per tap slab (8KB)

    __shared__ unsigned short featL[2][FCAP * 64];   // 2 x 32KB
    __shared__ unsigned short Wl[2][3 * SLAB];       // 2 x 24KB
    __shared__ int   nbrS[128 * 27];                 // 13.5KB
    __shared__ int   loS[9];
    __shared__ float red[4][2][64];

    const int tid  = threadIdx.x;
    const int lane = tid & 63;
    const int wv   = tid >> 6;
    const int colb = lane & 15;
    const int kgrp = lane >> 4;

    const int nwg = gridDim.x;
    const int q   = nwg >> 3, r8 = nwg & 7;
    const int xcd = blockIdx.x & 7, pos = blockIdx.x >> 3;
    const int wg  = (xcd < r8 ? xcd * (q + 1) : r8 * (q + 1) + (xcd - r8) * q) + pos;
    const int m0  = wg * 128;

    // ---- stage neighbor table + init group minima
    {
        const int* src = nbr + (size_t)m0 * 27;
        if (m0 + 128 <= M_ROWS) {
            #pragma unroll 1
            for (int i = tid; i < 864; i += 256)
                ((int4*)nbrS)[i] = ((const int4*)src)[i];
        } else {
            #pragma unroll 1
            for (int i = tid; i < 3456; i += 256) {
                int r = i / 27;
                nbrS[i] = (m0 + r < M_ROWS) ? src[i] : -1;
            }
        }
        if (tid < 9) loS[tid] = 0x7fffffff;
    }
    __syncthreads();
    // ---- per-group min over valid idx
    #pragma unroll 1
    for (int i = tid; i < 3456; i += 256) {
        int v = nbrS[i];
        if (v >= 0) atomicMin(&loS[(i % 27) / 3], v);
    }
    __syncthreads();

    auto stageF = [&](int g, int b) {
        int lg = loS[g]; if (lg == 0x7fffffff) lg = 0;
        const unsigned short* gp0 = fBs + (size_t)lg * 64;
        #pragma unroll
        for (int r = 0; r < 8; ++r) {
            const void* gp = gp0 + (size_t)(r * 256 + tid) * 8;
            void* lp = &featL[b][(size_t)(r * 256 + wv * 64) * 8];
            gload_lds16(gp, lp);
        }
    };
    auto stageWg = [&](int g, int b) {
        const unsigned short* gp0 = WTs + (size_t)(3 * g) * SLAB;
        #pragma unroll
        for (int r = 0; r < 6; ++r) {
            const void* gp = gp0 + (size_t)(r * 256 + tid) * 8;
            void* lp = &Wl[b][(size_t)(r * 256 + wv * 64) * 8];
            gload_lds16(gp, lp);
        }
    };

    f32x4 acc[2][4] = {};

    auto dotap = [&](int k, int slab, int b, int lg) {
        bf16x8 a[2][2];
        #pragma unroll
        for (int st = 0; st < 2; ++st) {
            int rloc = wv * 32 + st * 16 + colb;
            int idx = nbrS[rloc * 27 + k];
            if (idx < 0) {
                a[st][0] = bfzero(); a[st][1] = bfzero();
            } else {
                int xm = (idx & 7) << 4;
                unsigned off = (unsigned)(idx - lg);
                if (off < (unsigned)FCAP) {
                    const char* base = (const char*)&featL[b][0] + (size_t)off * 128;
                    a[st][0] = *(const bf16x8*)(base + ((kgrp * 16 +  0) ^ xm));
                    a[st][1] = *(const bf16x8*)(base + ((kgrp * 16 + 64) ^ xm));
                } else {
                    const char* gb = (const char*)(fBs + (size_t)idx * 64);
                    a[st][0] = *(const bf16x8*)(gb + ((kgrp * 16 +  0) ^ xm));
                    a[st][1] = *(const bf16x8*)(gb + ((kgrp * 16 + 64) ^ xm));
                }
            }
        }
        bf16x8 w[4][2];
        const char* wbase = (const char*)&Wl[b][0] + (size_t)slab * SLAB * 2;
        #pragma unroll
        for (int n = 0; n < 4; ++n) {
            int r  = n * 16 + colb;
            int xm = (r & 7) << 4;
            #pragma unroll
            for (int s = 0; s < 2; ++s) {
                int phys = r * 128 + ((kgrp * 16 + s * 64) ^ xm);
                w[n][s] = *reinterpret_cast<const bf16x8*>(wbase + phys);
            }
        }
        #pragma unroll
        for (int st = 0; st < 2; ++st)
            #pragma unroll
            for (int n = 0; n < 4; ++n)
                #pragma unroll
                for (int s = 0; s < 2; ++s)
                    acc[st][n] = __builtin_amdgcn_mfma_f32_16x16x32_bf16(
                        a[st][s], w[n][s], acc[st][n], 0, 0, 0);
    };

    stageF(0, 0); stageWg(0, 0);
    __syncthreads();   // drains stage(0)

    int buf = 0;
    #pragma unroll 1
    for (int g = 0; g < 9; ++g) {
        if (g + 1 < 9) { stageF(g + 1, buf ^ 1); stageWg(g + 1, buf ^ 1); }
        int lg = loS[g]; if (lg == 0x7fffffff) lg = 0;
        #pragma unroll
        for (int t3 = 0; t3 < 3; ++t3) dotap(3 * g + t3, t3, buf, lg);
        if (g + 1 < 9) __syncthreads();   // drains stage(g+1), dbuf handoff
        buf ^= 1;
    }

    // C write (linear). C/D layout: col=lane&15, row=(lane>>4)*4+j  [m89/m91]
    #pragma unroll
    for (int st = 0; st < 2; ++st) {
        int rbase = m0 + wv * 32 + st * 16 + kgrp * 4;
        #pragma unroll
        for (int j = 0; j < 4; ++j) {
            int row = rbase + j;
            if (row < M_ROWS) {
                if (OUTBF) {
                    unsigned short* o = (unsigned short*)outp;
                    #pragma unroll
                    for (int n = 0; n < 4; ++n)
                        o[(size_t)row * 64 + n * 16 + colb] = f2bf(acc[st][n][j]);
                } else {
                    float* o = (float*)outp;
                    #pragma unroll
                    for (int n = 0; n < 4; ++n)
                        o[(size_t)row * 64 + n * 16 + colb] = acc[st][n][j];
                }
            }
        }
    }

    // Fused BN partial stats
    float s4[4], q4[4];
    #pragma unroll
    for (int n = 0; n < 4; ++n) {
        float s = 0.f, qq = 0.f;
        #pragma unroll
        for (int st = 0; st < 2; ++st)
            #pragma unroll
            for (int j = 0; j < 4; ++j) {
                float v = acc[st][n][j];
                s += v; qq += v * v;
            }
        s4[n] = s; q4[n] = qq;
    }
    #pragma unroll
    for (int n = 0; n < 4; ++n) {
        s4[n] += __shfl_xor(s4[n], 16); s4[n] += __shfl_xor(s4[n], 32);
        q4[n] += __shfl_xor(q4[n], 16); q4[n] += __shfl_xor(q4[n], 32);
    }
    if (kgrp == 0) {
        #pragma unroll
        for (int n = 0; n < 4; ++n) {
            red[wv][0][n * 16 + colb] = s4[n];
            red[wv][1][n * 16 + colb] = q4[n];
        }
    }
    __syncthreads();
    if (tid < 64) {
        float S = red[0][0][tid] + red[1][0][tid] + red[2][0][tid] + red[3][0][tid];
        float Q = red[0][1][tid] + red[1][1][tid] + red[2][1][tid] + red[3][1][tid];
        part[(size_t)wg * 128 + tid]      = S;
        part[(size_t)wg * 128 + 64 + tid] = Q;
    }
}

// ---------------------------------------------------------------------------
// Reduce block partials -> per-channel scale/shift (1024 thr, 16 groups).
// ---------------------------------------------------------------------------
__global__ __launch_bounds__(1024) void bn_finalize(
    const float* __restrict__ part, int nblocks,
    const float* __restrict__ gg, const float* __restrict__ bb,
    float* __restrict__ ss, int M)
{
    const int tid = threadIdx.x;
    const int c   = tid & 63;
    const int grp = tid >> 6;
    float S = 0.f, Q = 0.f;
    int i = grp;
    for (; i + 48 < nblocks; i += 64) {
        float a0 = part[(size_t)(i     ) * 128 + c];
        float a1 = part[(size_t)(i + 16) * 128 + c];
        float a2 = part[(size_t)(i + 32) * 128 + c];
        float a3 = part[(size_t)(i + 48) * 128 + c];
        float q0 = part[(size_t)(i     ) * 128 + 64 + c];
        float q1 = part[(size_t)(i + 16) * 128 + 64 + c];
        float q2 = part[(size_t)(i + 32) * 128 + 64 + c];
        float q3 = part[(size_t)(i + 48) * 128 + 64 + c];
        S += a0 + a1 + a2 + a3;
        Q += q0 + q1 + q2 + q3;
    }
    for (; i < nblocks; i += 16) {
        S += part[(size_t)i * 128 + c];
        Q += part[(size_t)i * 128 + 64 + c];
    }
    __shared__ float sh[2][16][64];
    sh[0][grp][c] = S; sh[1][grp][c] = Q;
    __syncthreads();
    if (tid < 64) {
        float Sa = 0.f, Qa = 0.f;
        #pragma unroll
        for (int j = 0; j < 16; ++j) { Sa += sh[0][j][tid]; Qa += sh[1][j][tid]; }
        float mean = Sa / (float)M;
        float var  = Qa / (float)M - mean * mean;
        float rstd = rsqrtf(var + EPS);
        float sc = gg[tid] * rstd;
        ss[tid]      = sc;
        ss[64 + tid] = bb[tid] - mean * sc;
    }
}

// ---------------------------------------------------------------------------
// BN apply. INBF: bf16 input. BF16OUT: bf16 out. RES: +bf16 residual.
// RELU. OUTSWZ: XOR-swizzle output rows (feeds bulk-staged conv).
// ---------------------------------------------------------------------------
template<bool INBF, bool BF16OUT, bool RES, bool RELU, bool OUTSWZ>
__global__ __launch_bounds__(256) void bn_apply(
    const void* __restrict__ yp, const float* __restrict__ ss,
    const unsigned short* __restrict__ res, void* __restrict__ out, int n8)
{
    for (int i = blockIdx.x * 256 + threadIdx.x; i < n8; i += gridDim.x * 256) {
        float v[8];
        if (INBF) {
            u16x8 u = ((const u16x8*)yp)[i];
            #pragma unroll
            for (int j = 0; j < 8; ++j) v[j] = bf2f(u[j]);
        } else {
            float4 a = ((const float4*)yp)[2 * i];
            float4 b = ((const float4*)yp)[2 * i + 1];
            v[0] = a.x; v[1] = a.y; v[2] = a.z; v[3] = a.w;
            v[4] = b.x; v[5] = b.y; v[6] = b.z; v[7] = b.w;
        }
        int c0 = (i * 8) & 63;
        #pragma unroll
        for (int j = 0; j < 8; ++j)
            v[j] = v[j] * ss[c0 + j] + ss[64 + c0 + j];
        if (RES) {
            u16x8 rv = ((const u16x8*)res)[i];
            #pragma unroll
            for (int j = 0; j < 8; ++j) v[j] += bf2f(rv[j]);
        }
        if (RELU) {
            #pragma unroll
            for (int j = 0; j < 8; ++j) v[j] = fmaxf(v[j], 0.f);
        }
        if (BF16OUT) {
            u16x8 o;
            #pragma unroll
            for (int j = 0; j < 8; ++j) o[j] = f2bf(v[j]);
            int oi = i;
            if (OUTSWZ) oi = (i & ~7) | ((i & 7) ^ ((i >> 3) & 7));
            ((u16x8*)out)[oi] = o;
        } else {
            float4 oa, ob;
            oa.x = v[0]; oa.y = v[1]; oa.z = v[2]; oa.w = v[3];
            ob.x = v[4]; ob.y = v[5]; ob.z = v[6]; ob.w = v[7];
            ((float4*)out)[2 * i]     = oa;
            ((float4*)out)[2 * i + 1] = ob;
        }
    }
}

// ---------------------------------------------------------------------------
extern "C" void kernel_launch(void* const* d_in, const int* in_sizes, int n_in,
                              void* d_out, int out_size, void* d_ws, size_t ws_size,
                              hipStream_t stream)
{
    const float* x_feats = (const float*)d_in[0];
    const float* w_down  = (const float*)d_in[1];
    const float* g_down  = (const float*)d_in[2];
    const float* b_down  = (const float*)d_in[3];
    const float* w_proj  = (const float*)d_in[4];
    const float* g_p     = (const float*)d_in[5];
    const float* b_p     = (const float*)d_in[6];
    const float* w1      = (const float*)d_in[7];
    const float* g1      = (const float*)d_in[8];
    const float* b1      = (const float*)d_in[9];
    const float* w2      = (const float*)d_in[10];
    const float* g2      = (const float*)d_in[11];
    const float* b2      = (const float*)d_in[12];
    const int*   nbr_down = (const int*)d_in[13];
    const int*   nbr_sub  = (const int*)d_in[14];
    float* out = (float*)d_out;

    const int M = M_ROWS;
    const int conv_grid = (M + 127) / 128;       // 782
    const size_t feat4 = (size_t)M * CO * 4;
    const size_t feat2 = (size_t)(M + 1 + FCAP) * CO * 2;  // + dummy + bulk slack
    auto align = [](size_t x) { return (x + 255) & ~(size_t)255; };

    char* ws = (char*)d_ws;
    size_t off = 0;
    unsigned short* xin16 = (unsigned short*)(ws + off); off += align((size_t)(N_IN + 1) * C_IN * 2);
    unsigned short* wdT   = (unsigned short*)(ws + off); off += align((size_t)8 * CO * C_IN * 2);
    unsigned short* wpT   = (unsigned short*)(ws + off); off += align((size_t)1 * CO * CO * 2);
    unsigned short* w1T   = (unsigned short*)(ws + off); off += align((size_t)27 * CO * CO * 2);
    unsigned short* w2T   = (unsigned short*)(ws + off); off += align((size_t)27 * CO * CO * 2);
    float* Y    = (float*)(ws + off); off += align(feat4);
    unsigned short* bufRb = (unsigned short*)(ws + off); off += align(feat2);
    unsigned short* xB = (unsigned short*)(ws + off); off += align(feat2);   // SWIZZLED
    unsigned short* zB = (unsigned short*)(ws + off); off += align(feat2);   // SWIZZLED
    float* part = (float*)(ws + off); off += align((size_t)1024 * 128 * 4);
    float* ss0  = (float*)(ws + off);
    float* ss1  = ss0 + 128;
    float* ss2  = ss1 + 128;
    float* ss3  = ss2 + 128;

    unsigned short* Yb = (unsigned short*)Y;   // bf16 raw-out aliases Y space

    const int n8 = M * CO / 8;
    const int ew_grid = 2048;

    // zero dummy + slack rows (idx<0 / padding reads land here; zero stats)
    hipMemsetAsync(xin16 + (size_t)N_IN * C_IN, 0, C_IN * 2, stream);
    hipMemsetAsync(xB + (size_t)M * CO, 0, (1 + FCAP) * CO * 2, stream);
    hipMemsetAsync(zB + (size_t)M * CO, 0, (1 + FCAP) * CO * 2, stream);

    // 0) input + weight casts (weights swizzled)
    {
        int nf8 = N_IN * C_IN / 8;
        cvt_bf16<<<(nf8 + 255) / 256, 256, 0, stream>>>(x_feats, xin16, nf8);
        int t;
        t = 8 * C_IN * CO;  wt_cvt_swz<<<(t + 255) / 256, 256, 0, stream>>>(w_down, wdT, t, C_IN);
        t = CO * CO;        wt_cvt_swz<<<(t + 255) / 256, 256, 0, stream>>>(w_proj, wpT, t, CO);
        t = 27 * CO * CO;   wt_cvt_swz<<<(t + 255) / 256, 256, 0, stream>>>(w1, w1T, t, CO);
        t = 27 * CO * CO;   wt_cvt_swz<<<(t + 255) / 256, 256, 0, stream>>>(w2, w2T, t, CO);
    }

    // 1) down conv -> Yb (linear bf16) ; x = relu(bn(Yb)) -> xB (SWIZZLED)
    spconv_mfma<C_IN, 8, 8, true, true, false><<<conv_grid, 256, 0, stream>>>(
        xin16, N_IN, nbr_down, wdT, Yb, part);
    bn_finalize<<<1, 1024, 0, stream>>>(part, conv_grid, g_down, b_down, ss0, M);
    bn_apply<true, true, false, true, true><<<ew_grid, 256, 0, stream>>>(Yb, ss0, nullptr, xB, n8);

    // 2) proj (reads swizzled xB): res = bn(x @ w_proj) -> bufRb (linear)
    spconv_mfma<CO, 1, 1, false, true, true><<<conv_grid, 256, 0, stream>>>(
        xB, M, nullptr, wpT, Yb, part);
    bn_finalize<<<1, 1024, 0, stream>>>(part, conv_grid, g_p, b_p, ss1, M);
    bn_apply<true, true, false, false, false><<<ew_grid, 256, 0, stream>>>(Yb, ss1, nullptr, bufRb, n8);

    // 3) conv1 (bulk-staged): z = relu(bn(spconv(x, nbr_sub, w1))) -> zB (SWIZZLED)
    spconv_sub27<true><<<conv_grid, 256, 0, stream>>>(xB, nbr_sub, w1T, Yb, part);
    bn_finalize<<<1, 1024, 0, stream>>>(part, conv_grid, g1, b1, ss2, M);
    bn_apply<true, true, false, true, true><<<ew_grid, 256, 0, stream>>>(Yb, ss2, nullptr, zB, n8);

    // 4) conv2 (bulk-staged): out = relu(bn(spconv(z, nbr_sub, w2)) + res)
    spconv_sub27<false><<<conv_grid, 256, 0, stream>>>(zB, nbr_sub, w2T, Y, part);
    bn_finalize<<<1, 1024, 0, stream>>>(part, conv_grid, g2, b2, ss3, M);
    bn_apply<false, false, true, true, false><<<ew_grid, 256, 0, stream>>>(Y, ss3, bufRb, out, n8);
}

// Round 15
// 171.674 us; speedup vs baseline: 1.4799x; 1.4799x over previous
//
#include <hip/hip_runtime.h>

// Problem constants (match reference setup_inputs)
static constexpr int M_ROWS = 100000;
static constexpr int N_IN   = 150000;
static constexpr int C_IN   = 32;
static constexpr int CO     = 64;
static constexpr float EPS  = 1e-5f;

typedef __bf16 bf16x8 __attribute__((ext_vector_type(8)));
typedef float  f32x4  __attribute__((ext_vector_type(4)));
typedef unsigned short u16x8 __attribute__((ext_vector_type(8)));
typedef short  short8 __attribute__((ext_vector_type(8)));
typedef unsigned int u32;

static __device__ __forceinline__ unsigned short f2bf(float f) {
    unsigned int u = __builtin_bit_cast(unsigned int, f);
    u += 0x7fff + ((u >> 16) & 1);              // round-to-nearest-even
    return (unsigned short)(u >> 16);
}
static __device__ __forceinline__ float bf2f(unsigned short h) {
    unsigned int u = ((unsigned int)h) << 16;
    return __builtin_bit_cast(float, u);
}

// async global->LDS, 16B per lane. lds ptr must be wave-uniform.
static __device__ __forceinline__ void gload_lds16(const void* g, void* l) {
    __builtin_amdgcn_global_load_lds(
        (const __attribute__((address_space(1))) u32*)g,
        (__attribute__((address_space(3))) u32*)l, 16, 0, 0);
}

// ---------------------------------------------------------------------------
// f32 -> bf16 elementwise cast (8 elems/thread)
// ---------------------------------------------------------------------------
__global__ __launch_bounds__(256) void cvt_bf16(
    const float* __restrict__ in, unsigned short* __restrict__ out, int n8)
{
    int i = blockIdx.x * 256 + threadIdx.x;
    if (i >= n8) return;
    float4 a = ((const float4*)in)[2 * i];
    float4 b = ((const float4*)in)[2 * i + 1];
    u16x8 v;
    v[0] = f2bf(a.x); v[1] = f2bf(a.y); v[2] = f2bf(a.z); v[3] = f2bf(a.w);
    v[4] = f2bf(b.x); v[5] = f2bf(b.y); v[6] = f2bf(b.z); v[7] = f2bf(b.w);
    ((u16x8*)out)[i] = v;
}

// ---------------------------------------------------------------------------
// ALL weight tensors cast + transpose + XOR-swizzle in one launch.
// ranges: [0,16384)=w_down(cin32), [16384,20480)=w_proj,
//         [20480,131072)=w1, [131072,241664)=w2   (cin64 for the last 3)
// ---------------------------------------------------------------------------
__global__ __launch_bounds__(256) void wt_cvt_all(
    const float* __restrict__ wd, const float* __restrict__ wp,
    const float* __restrict__ w1, const float* __restrict__ w2,
    unsigned short* __restrict__ wdT, unsigned short* __restrict__ wpT,
    unsigned short* __restrict__ w1T, unsigned short* __restrict__ w2T)
{
    int t = blockIdx.x * 256 + threadIdx.x;
    if (t >= 241664) return;
    const float* W; unsigned short* WT; int cin, tt;
    if (t < 16384)       { W = wd; WT = wdT; cin = 32; tt = t; }
    else if (t < 20480)  { W = wp; WT = wpT; cin = 64; tt = t - 16384; }
    else if (t < 131072) { W = w1; WT = w1T; cin = 64; tt = t - 20480; }
    else                 { W = w2; WT = w2T; cin = 64; tt = t - 131072; }
    int k  = tt / (cin * 64);
    int r  = tt - k * (cin * 64);
    int ci = r >> 6;
    int co = r & 63;
    int xm = (cin == 64) ? ((co & 7) << 4) : ((co & 3) << 4);
    int phys = co * (cin * 2) + ((ci * 2) ^ xm);
    WT[(size_t)k * cin * 64 + (phys >> 1)] = f2bf(W[tt]);
}

// ---------------------------------------------------------------------------
// MFMA gather-conv + fused BN partial stats.
// 512 threads = 8 waves x (ST=2 x 16) rows = 256 rows/block, grid 391.
// Combines r10 (256 rows/block: half the stage insts + barrier rounds per
// row) with r12 (8-wave TLP). LDS ~48KB -> 3 blocks/CU = 24 waves/CU.
// Proven per-tap schedule: gather(k) -> stageW(k+1) -> compute(k) -> barrier.
// Weight slab staged with exactly 1 global_load_lds per thread (CIN=64).
// Invalid neighbors -> dummy zero row at index nZero.
// ---------------------------------------------------------------------------
template<int CIN, int KOFF, bool GATHER, bool OUTBF>
__global__ __launch_bounds__(512) void spconv_mfma(
    const unsigned short* __restrict__ fB,   // [rows+1][CIN], last row zero
    int nZero,
    const int*   __restrict__ nbr,
    const unsigned short* __restrict__ WTs,  // swizzled slabs
    void* __restrict__ outp,
    float* __restrict__ part)
{
    constexpr int KS     = CIN / 32;
    constexpr int ST     = 2;
    constexpr int ROWS   = 256;                 // rows per block
    constexpr int SLAB   = CIN * 64;            // ushorts per tap slab
    constexpr int SWAVES = CIN / 8;             // waves staging 1KB each

    __shared__ unsigned short Wl[2][SLAB];
    __shared__ int nbrS[GATHER ? ROWS * KOFF : 4];
    __shared__ float red[8][2][64];

    const int tid  = threadIdx.x;
    const int lane = tid & 63;
    const int wv   = tid >> 6;                  // 0..7
    const int colb = lane & 15;
    const int kgrp = lane >> 4;

    // bijective XCD-chunk swizzle (m204): contiguous m-chunk per XCD
    const int nwg = gridDim.x;
    const int q   = nwg >> 3, r8 = nwg & 7;
    const int xcd = blockIdx.x & 7, pos = blockIdx.x >> 3;
    const int wg  = (xcd < r8 ? xcd * (q + 1) : r8 * (q + 1) + (xcd - r8) * q) + pos;
    const int m0  = wg * ROWS;

    auto stageW = [&](int k, int b) {
        if (wv < SWAVES) {
            const unsigned short* gp = WTs + (size_t)k * SLAB + wv * 512 + lane * 8;
            void* lp = &Wl[b][wv * 512];
            gload_lds16(gp, lp);
        }
    };

    // stage tap-0 weights + (if gathering) the neighbor table
    stageW(0, 0);
    if (GATHER) {
        const int* src = nbr + (size_t)m0 * KOFF;
        constexpr int TOT = ROWS * KOFF;
        if (m0 + ROWS <= M_ROWS) {
            #pragma unroll 1
            for (int i = tid; i < TOT / 4; i += 512)
                ((int4*)nbrS)[i] = ((const int4*)src)[i];
        } else {
            #pragma unroll 1
            for (int i = tid; i < TOT; i += 512) {
                int r = i / KOFF;
                nbrS[i] = (m0 + r < M_ROWS) ? src[i] : -1;
            }
        }
    }
    __syncthreads();   // drains stage(0) vmcnt + orders nbrS before any gather

    auto gatherA = [&](int k, bf16x8 (&dst)[ST][KS]) {
        #pragma unroll
        for (int st = 0; st < ST; ++st) {
            int rloc = wv * (ST * 16) + st * 16 + colb;
            int idx;
            if (GATHER) idx = nbrS[rloc * KOFF + k];
            else        idx = (m0 + rloc < M_ROWS) ? (m0 + rloc) : -1;
            if (idx < 0) idx = nZero;
            const unsigned short* fp = fB + (size_t)idx * CIN + kgrp * 8;
            #pragma unroll
            for (int s = 0; s < KS; ++s)
                dst[st][s] = *reinterpret_cast<const bf16x8*>(fp + s * 32);
        }
    };

    f32x4 acc[ST][4] = {};

    auto compute = [&](int buf, const bf16x8 (&a)[ST][KS]) {
        bf16x8 w[4][KS];
        const char* base = (const char*)&Wl[0][0] + (size_t)buf * SLAB * 2;
        #pragma unroll
        for (int n = 0; n < 4; ++n) {
            int r  = n * 16 + colb;
            int xm = (CIN == 64) ? ((r & 7) << 4) : ((r & 3) << 4);
            #pragma unroll
            for (int s = 0; s < KS; ++s) {
                int c2 = kgrp * 16 + s * 64;
                int phys = r * (CIN * 2) + (c2 ^ xm);
                w[n][s] = *reinterpret_cast<const bf16x8*>(base + phys);
            }
        }
        #pragma unroll
        for (int st = 0; st < ST; ++st)
            #pragma unroll
            for (int n = 0; n < 4; ++n)
                #pragma unroll
                for (int s = 0; s < KS; ++s)
                    acc[st][n] = __builtin_amdgcn_mfma_f32_16x16x32_bf16(
                        a[st][s], w[n][s], acc[st][n], 0, 0, 0);
    };

    // proven schedule: gather(k) -> stage(k+1) -> compute(k) -> barrier
    #pragma unroll 1
    for (int k = 0; k < KOFF; ++k) {
        bf16x8 a[ST][KS];
        gatherA(k, a);
        if (k + 1 < KOFF) stageW(k + 1, (k + 1) & 1);
        compute(k & 1, a);
        if (k + 1 < KOFF) __syncthreads();  // dbuf handoff (drains stage k+1)
    }

    // C write. C/D layout: col = lane&15, row = (lane>>4)*4 + j  [m89/m91]
    #pragma unroll
    for (int st = 0; st < ST; ++st) {
        int rbase = m0 + wv * (ST * 16) + st * 16 + kgrp * 4;
        #pragma unroll
        for (int j = 0; j < 4; ++j) {
            int row = rbase + j;
            if (row < M_ROWS) {
                if (OUTBF) {
                    unsigned short* o = (unsigned short*)outp;
                    #pragma unroll
                    for (int n = 0; n < 4; ++n)
                        o[(size_t)row * 64 + n * 16 + colb] = f2bf(acc[st][n][j]);
                } else {
                    float* o = (float*)outp;
                    #pragma unroll
                    for (int n = 0; n < 4; ++n)
                        o[(size_t)row * 64 + n * 16 + colb] = acc[st][n][j];
                }
            }
        }
    }

    // Fused BN partial stats (zero rows contribute exact zeros)
    float s4[4], q4[4];
    #pragma unroll
    for (int n = 0; n < 4; ++n) {
        float s = 0.f, qq = 0.f;
        #pragma unroll
        for (int st = 0; st < ST; ++st)
            #pragma unroll
            for (int j = 0; j < 4; ++j) {
                float v = acc[st][n][j];
                s += v; qq += v * v;
            }
        s4[n] = s; q4[n] = qq;
    }
    #pragma unroll
    for (int n = 0; n < 4; ++n) {
        s4[n] += __shfl_xor(s4[n], 16); s4[n] += __shfl_xor(s4[n], 32);
        q4[n] += __shfl_xor(q4[n], 16); q4[n] += __shfl_xor(q4[n], 32);
    }
    if (kgrp == 0) {
        #pragma unroll
        for (int n = 0; n < 4; ++n) {
            red[wv][0][n * 16 + colb] = s4[n];
            red[wv][1][n * 16 + colb] = q4[n];
        }
    }
    __syncthreads();
    if (tid < 64) {
        float S = 0.f, Q = 0.f;
        #pragma unroll
        for (int w8 = 0; w8 < 8; ++w8) { S += red[w8][0][tid]; Q += red[w8][1][tid]; }
        part[(size_t)wg * 128 + tid]      = S;
        part[(size_t)wg * 128 + 64 + tid] = Q;
    }
}

// ---------------------------------------------------------------------------
// Reduce block partials -> per-channel scale/shift (1024 thr, 16 groups).
// ---------------------------------------------------------------------------
__global__ __launch_bounds__(1024) void bn_finalize(
    const float* __restrict__ part, int nblocks,
    const float* __restrict__ gg, const float* __restrict__ bb,
    float* __restrict__ ss, int M)
{
    const int tid = threadIdx.x;
    const int c   = tid & 63;
    const int grp = tid >> 6;
    float S = 0.f, Q = 0.f;
    int i = grp;
    for (; i + 48 < nblocks; i += 64) {
        float a0 = part[(size_t)(i     ) * 128 + c];
        float a1 = part[(size_t)(i + 16) * 128 + c];
        float a2 = part[(size_t)(i + 32) * 128 + c];
        float a3 = part[(size_t)(i + 48) * 128 + c];
        float q0 = part[(size_t)(i     ) * 128 + 64 + c];
        float q1 = part[(size_t)(i + 16) * 128 + 64 + c];
        float q2 = part[(size_t)(i + 32) * 128 + 64 + c];
        float q3 = part[(size_t)(i + 48) * 128 + 64 + c];
        S += a0 + a1 + a2 + a3;
        Q += q0 + q1 + q2 + q3;
    }
    for (; i < nblocks; i += 16) {
        S += part[(size_t)i * 128 + c];
        Q += part[(size_t)i * 128 + 64 + c];
    }
    __shared__ float sh[2][16][64];
    sh[0][grp][c] = S; sh[1][grp][c] = Q;
    __syncthreads();
    if (tid < 64) {
        float Sa = 0.f, Qa = 0.f;
        #pragma unroll
        for (int j = 0; j < 16; ++j) { Sa += sh[0][j][tid]; Qa += sh[1][j][tid]; }
        float mean = Sa / (float)M;
        float var  = Qa / (float)M - mean * mean;
        float rstd = rsqrtf(var + EPS);
        float sc = gg[tid] * rstd;
        ss[tid]      = sc;
        ss[64 + tid] = bb[tid] - mean * sc;
    }
}

// ---------------------------------------------------------------------------
// BN apply, 8 channels/thread. INBF: bf16 input. BF16OUT: bf16 out.
// RES: + bf16 residual. RELU.
// ---------------------------------------------------------------------------
template<bool INBF, bool BF16OUT, bool RES, bool RELU>
__global__ __launch_bounds__(256) void bn_apply(
    const void* __restrict__ yp, const float* __restrict__ ss,
    const unsigned short* __restrict__ res, void* __restrict__ out, int n8)
{
    for (int i = blockIdx.x * 256 + threadIdx.x; i < n8; i += gridDim.x * 256) {
        float v[8];
        if (INBF) {
            u16x8 u = ((const u16x8*)yp)[i];
            #pragma unroll
            for (int j = 0; j < 8; ++j) v[j] = bf2f(u[j]);
        } else {
            float4 a = ((const float4*)yp)[2 * i];
            float4 b = ((const float4*)yp)[2 * i + 1];
            v[0] = a.x; v[1] = a.y; v[2] = a.z; v[3] = a.w;
            v[4] = b.x; v[5] = b.y; v[6] = b.z; v[7] = b.w;
        }
        int c0 = (i * 8) & 63;
        #pragma unroll
        for (int j = 0; j < 8; ++j)
            v[j] = v[j] * ss[c0 + j] + ss[64 + c0 + j];
        if (RES) {
            u16x8 rv = ((const u16x8*)res)[i];
            #pragma unroll
            for (int j = 0; j < 8; ++j) v[j] += bf2f(rv[j]);
        }
        if (RELU) {
            #pragma unroll
            for (int j = 0; j < 8; ++j) v[j] = fmaxf(v[j], 0.f);
        }
        if (BF16OUT) {
            u16x8 o;
            #pragma unroll
            for (int j = 0; j < 8; ++j) o[j] = f2bf(v[j]);
            ((u16x8*)out)[i] = o;
        } else {
            float4 oa, ob;
            oa.x = v[0]; oa.y = v[1]; oa.z = v[2]; oa.w = v[3];
            ob.x = v[4]; ob.y = v[5]; ob.z = v[6]; ob.w = v[7];
            ((float4*)out)[2 * i]     = oa;
            ((float4*)out)[2 * i + 1] = ob;
        }
    }
}

// ---------------------------------------------------------------------------
extern "C" void kernel_launch(void* const* d_in, const int* in_sizes, int n_in,
                              void* d_out, int out_size, void* d_ws, size_t ws_size,
                              hipStream_t stream)
{
    const float* x_feats = (const float*)d_in[0];
    const float* w_down  = (const float*)d_in[1];
    const float* g_down  = (const float*)d_in[2];
    const float* b_down  = (const float*)d_in[3];
    const float* w_proj  = (const float*)d_in[4];
    const float* g_p     = (const float*)d_in[5];
    const float* b_p     = (const float*)d_in[6];
    const float* w1      = (const float*)d_in[7];
    const float* g1      = (const float*)d_in[8];
    const float* b1      = (const float*)d_in[9];
    const float* w2      = (const float*)d_in[10];
    const float* g2      = (const float*)d_in[11];
    const float* b2      = (const float*)d_in[12];
    const int*   nbr_down = (const int*)d_in[13];
    const int*   nbr_sub  = (const int*)d_in[14];
    float* out = (float*)d_out;

    const int M = M_ROWS;
    const int conv_grid = (M + 255) / 256;       // 391 (256 rows/block)
    const size_t feat2 = (size_t)(M + 1) * CO * 2;   // bf16 (+zero row)
    auto align = [](size_t x) { return (x + 255) & ~(size_t)255; };

    char* ws = (char*)d_ws;
    size_t off = 0;
    unsigned short* xin16 = (unsigned short*)(ws + off); off += align((size_t)(N_IN + 1) * C_IN * 2);
    unsigned short* wdT   = (unsigned short*)(ws + off); off += align((size_t)8 * CO * C_IN * 2);
    unsigned short* wpT   = (unsigned short*)(ws + off); off += align((size_t)1 * CO * CO * 2);
    unsigned short* w1T   = (unsigned short*)(ws + off); off += align((size_t)27 * CO * CO * 2);
    unsigned short* w2T   = (unsigned short*)(ws + off); off += align((size_t)27 * CO * CO * 2);
    unsigned short* Yb    = (unsigned short*)(ws + off); off += align(feat2);  // raw conv out (bf16)
    unsigned short* bufRb = (unsigned short*)(ws + off); off += align(feat2);  // residual bf16
    unsigned short* xB    = (unsigned short*)(ws + off); off += align(feat2);
    unsigned short* zB    = (unsigned short*)(ws + off); off += align(feat2);
    float* part = (float*)(ws + off); off += align((size_t)1024 * 128 * 4);
    float* ss0  = (float*)(ws + off);
    float* ss1  = ss0 + 128;
    float* ss2  = ss1 + 128;
    float* ss3  = ss2 + 128;

    const int n8 = M * CO / 8;
    const int ew_grid = 2048;

    // zero dummy rows (idx<0 gathers land here)
    hipMemsetAsync(xin16 + (size_t)N_IN * C_IN, 0, C_IN * 2, stream);
    hipMemsetAsync(xB + (size_t)M * CO, 0, CO * 2, stream);
    hipMemsetAsync(zB + (size_t)M * CO, 0, CO * 2, stream);

    // 0) input cast + ALL weight casts (one kernel)
    {
        int nf8 = N_IN * C_IN / 8;
        cvt_bf16<<<(nf8 + 255) / 256, 256, 0, stream>>>(x_feats, xin16, nf8);
        wt_cvt_all<<<(241664 + 255) / 256, 256, 0, stream>>>(
            w_down, w_proj, w1, w2, wdT, wpT, w1T, w2T);
    }

    // 1) down conv -> Yb bf16 (+stats); x = relu(bn(Yb)) -> xB
    spconv_mfma<C_IN, 8, true, true><<<conv_grid, 512, 0, stream>>>(
        xin16, N_IN, nbr_down, wdT, Yb, part);
    bn_finalize<<<1, 1024, 0, stream>>>(part, conv_grid, g_down, b_down, ss0, M);
    bn_apply<true, true, false, true><<<ew_grid, 256, 0, stream>>>(Yb, ss0, nullptr, xB, n8);

    // 2) proj: res = bn(x @ w_proj) -> bufRb (bf16)
    spconv_mfma<CO, 1, false, true><<<conv_grid, 512, 0, stream>>>(
        xB, M, nullptr, wpT, Yb, part);
    bn_finalize<<<1, 1024, 0, stream>>>(part, conv_grid, g_p, b_p, ss1, M);
    bn_apply<true, true, false, false><<<ew_grid, 256, 0, stream>>>(Yb, ss1, nullptr, bufRb, n8);

    // 3) conv1: z = relu(bn(spconv(x, nbr_sub, w1))) -> zB
    spconv_mfma<CO, 27, true, true><<<conv_grid, 512, 0, stream>>>(
        xB, M, nbr_sub, w1T, Yb, part);
    bn_finalize<<<1, 1024, 0, stream>>>(part, conv_grid, g1, b1, ss2, M);
    bn_apply<true, true, false, true><<<ew_grid, 256, 0, stream>>>(Yb, ss2, nullptr, zB, n8);

    // 4) conv2: out = relu(bn(spconv(z, nbr_sub, w2)) + res)
    spconv_mfma<CO, 27, true, true><<<conv_grid, 512, 0, stream>>>(
        zB, M, nbr_sub, w2T, Yb, part);
    bn_finalize<<<1, 1024, 0, stream>>>(part, conv_grid, g2, b2, ss3, M);
    bn_apply<true, false, true, true><<<ew_grid, 256, 0, stream>>>(Yb, ss3, bufRb, out, n8);
}

// Round 16
// 158.741 us; speedup vs baseline: 1.6004x; 1.0815x over previous
//
#include <hip/hip_runtime.h>

// Problem constants (match reference setup_inputs)
static constexpr int M_ROWS = 100000;
static constexpr int N_IN   = 150000;
static constexpr int C_IN   = 32;
static constexpr int CO     = 64;
static constexpr float EPS  = 1e-5f;

typedef __bf16 bf16x8 __attribute__((ext_vector_type(8)));
typedef float  f32x4  __attribute__((ext_vector_type(4)));
typedef unsigned short u16x8 __attribute__((ext_vector_type(8)));
typedef short  short8 __attribute__((ext_vector_type(8)));
typedef unsigned int u32;

static __device__ __forceinline__ unsigned short f2bf(float f) {
    unsigned int u = __builtin_bit_cast(unsigned int, f);
    u += 0x7fff + ((u >> 16) & 1);              // round-to-nearest-even
    return (unsigned short)(u >> 16);
}
static __device__ __forceinline__ float bf2f(unsigned short h) {
    unsigned int u = ((unsigned int)h) << 16;
    return __builtin_bit_cast(float, u);
}
static __device__ __forceinline__ bf16x8 bfzero() {
    short8 z = {0,0,0,0,0,0,0,0};
    return __builtin_bit_cast(bf16x8, z);
}

// async global->LDS, 16B per lane. lds ptr must be wave-uniform.
static __device__ __forceinline__ void gload_lds16(const void* g, void* l) {
    __builtin_amdgcn_global_load_lds(
        (const __attribute__((address_space(1))) u32*)g,
        (__attribute__((address_space(3))) u32*)l, 16, 0, 0);
}

// ---------------------------------------------------------------------------
// f32 -> bf16 elementwise cast (8 elems/thread)
// ---------------------------------------------------------------------------
__global__ __launch_bounds__(256) void cvt_bf16(
    const float* __restrict__ in, unsigned short* __restrict__ out, int n8)
{
    int i = blockIdx.x * 256 + threadIdx.x;
    if (i >= n8) return;
    float4 a = ((const float4*)in)[2 * i];
    float4 b = ((const float4*)in)[2 * i + 1];
    u16x8 v;
    v[0] = f2bf(a.x); v[1] = f2bf(a.y); v[2] = f2bf(a.z); v[3] = f2bf(a.w);
    v[4] = f2bf(b.x); v[5] = f2bf(b.y); v[6] = f2bf(b.z); v[7] = f2bf(b.w);
    ((u16x8*)out)[i] = v;
}

// ---------------------------------------------------------------------------
// ALL weight tensors cast + transpose + XOR-swizzle in one launch.
// ---------------------------------------------------------------------------
__global__ __launch_bounds__(256) void wt_cvt_all(
    const float* __restrict__ wd, const float* __restrict__ wp,
    const float* __restrict__ w1, const float* __restrict__ w2,
    unsigned short* __restrict__ wdT, unsigned short* __restrict__ wpT,
    unsigned short* __restrict__ w1T, unsigned short* __restrict__ w2T)
{
    int t = blockIdx.x * 256 + threadIdx.x;
    if (t >= 241664) return;
    const float* W; unsigned short* WT; int cin, tt;
    if (t < 16384)       { W = wd; WT = wdT; cin = 32; tt = t; }
    else if (t < 20480)  { W = wp; WT = wpT; cin = 64; tt = t - 16384; }
    else if (t < 131072) { W = w1; WT = w1T; cin = 64; tt = t - 20480; }
    else                 { W = w2; WT = w2T; cin = 64; tt = t - 131072; }
    int k  = tt / (cin * 64);
    int r  = tt - k * (cin * 64);
    int ci = r >> 6;
    int co = r & 63;
    int xm = (cin == 64) ? ((co & 7) << 4) : ((co & 3) << 4);
    int phys = co * (cin * 2) + ((ci * 2) ^ xm);
    WT[(size_t)k * cin * 64 + (phys >> 1)] = f2bf(W[tt]);
}

// ---------------------------------------------------------------------------
// MFMA gather-conv + fused BN partial stats (r15-proven config).
// 512 threads = 8 waves x 32 rows = 256 rows/block, grid 391.
// Schedule: gather(k) -> stageW(k+1) -> compute(k) -> barrier.
// ---------------------------------------------------------------------------
template<int CIN, int KOFF, bool GATHER, bool OUTBF>
__global__ __launch_bounds__(512) void spconv_mfma(
    const unsigned short* __restrict__ fB,   // [rows+1][CIN], last row zero
    int nZero,
    const int*   __restrict__ nbr,
    const unsigned short* __restrict__ WTs,  // swizzled slabs
    void* __restrict__ outp,
    float* __restrict__ part)
{
    constexpr int KS     = CIN / 32;
    constexpr int ST     = 2;
    constexpr int ROWS   = 256;
    constexpr int SLAB   = CIN * 64;
    constexpr int SWAVES = CIN / 8;

    __shared__ unsigned short Wl[2][SLAB];
    __shared__ int nbrS[GATHER ? ROWS * KOFF : 4];
    __shared__ float red[8][2][64];

    const int tid  = threadIdx.x;
    const int lane = tid & 63;
    const int wv   = tid >> 6;
    const int colb = lane & 15;
    const int kgrp = lane >> 4;

    const int nwg = gridDim.x;
    const int q   = nwg >> 3, r8 = nwg & 7;
    const int xcd = blockIdx.x & 7, pos = blockIdx.x >> 3;
    const int wg  = (xcd < r8 ? xcd * (q + 1) : r8 * (q + 1) + (xcd - r8) * q) + pos;
    const int m0  = wg * ROWS;

    auto stageW = [&](int k, int b) {
        if (wv < SWAVES) {
            const unsigned short* gp = WTs + (size_t)k * SLAB + wv * 512 + lane * 8;
            void* lp = &Wl[b][wv * 512];
            gload_lds16(gp, lp);
        }
    };

    stageW(0, 0);
    if (GATHER) {
        const int* src = nbr + (size_t)m0 * KOFF;
        constexpr int TOT = ROWS * KOFF;
        if (m0 + ROWS <= M_ROWS) {
            #pragma unroll 1
            for (int i = tid; i < TOT / 4; i += 512)
                ((int4*)nbrS)[i] = ((const int4*)src)[i];
        } else {
            #pragma unroll 1
            for (int i = tid; i < TOT; i += 512) {
                int r = i / KOFF;
                nbrS[i] = (m0 + r < M_ROWS) ? src[i] : -1;
            }
        }
    }
    __syncthreads();

    auto gatherA = [&](int k, bf16x8 (&dst)[ST][KS]) {
        #pragma unroll
        for (int st = 0; st < ST; ++st) {
            int rloc = wv * (ST * 16) + st * 16 + colb;
            int idx;
            if (GATHER) idx = nbrS[rloc * KOFF + k];
            else        idx = (m0 + rloc < M_ROWS) ? (m0 + rloc) : -1;
            if (idx < 0) idx = nZero;
            const unsigned short* fp = fB + (size_t)idx * CIN + kgrp * 8;
            #pragma unroll
            for (int s = 0; s < KS; ++s)
                dst[st][s] = *reinterpret_cast<const bf16x8*>(fp + s * 32);
        }
    };

    f32x4 acc[ST][4] = {};

    auto compute = [&](int buf, const bf16x8 (&a)[ST][KS]) {
        bf16x8 w[4][KS];
        const char* base = (const char*)&Wl[0][0] + (size_t)buf * SLAB * 2;
        #pragma unroll
        for (int n = 0; n < 4; ++n) {
            int r  = n * 16 + colb;
            int xm = (CIN == 64) ? ((r & 7) << 4) : ((r & 3) << 4);
            #pragma unroll
            for (int s = 0; s < KS; ++s) {
                int c2 = kgrp * 16 + s * 64;
                int phys = r * (CIN * 2) + (c2 ^ xm);
                w[n][s] = *reinterpret_cast<const bf16x8*>(base + phys);
            }
        }
        #pragma unroll
        for (int st = 0; st < ST; ++st)
            #pragma unroll
            for (int n = 0; n < 4; ++n)
                #pragma unroll
                for (int s = 0; s < KS; ++s)
                    acc[st][n] = __builtin_amdgcn_mfma_f32_16x16x32_bf16(
                        a[st][s], w[n][s], acc[st][n], 0, 0, 0);
    };

    #pragma unroll 1
    for (int k = 0; k < KOFF; ++k) {
        bf16x8 a[ST][KS];
        gatherA(k, a);
        if (k + 1 < KOFF) stageW(k + 1, (k + 1) & 1);
        compute(k & 1, a);
        if (k + 1 < KOFF) __syncthreads();
    }

    // C write. C/D layout: col = lane&15, row = (lane>>4)*4 + j  [m89/m91]
    #pragma unroll
    for (int st = 0; st < ST; ++st) {
        int rbase = m0 + wv * (ST * 16) + st * 16 + kgrp * 4;
        #pragma unroll
        for (int j = 0; j < 4; ++j) {
            int row = rbase + j;
            if (row < M_ROWS) {
                if (OUTBF) {
                    unsigned short* o = (unsigned short*)outp;
                    #pragma unroll
                    for (int n = 0; n < 4; ++n)
                        o[(size_t)row * 64 + n * 16 + colb] = f2bf(acc[st][n][j]);
                } else {
                    float* o = (float*)outp;
                    #pragma unroll
                    for (int n = 0; n < 4; ++n)
                        o[(size_t)row * 64 + n * 16 + colb] = acc[st][n][j];
                }
            }
        }
    }

    // Fused BN partial stats
    float s4[4], q4[4];
    #pragma unroll
    for (int n = 0; n < 4; ++n) {
        float s = 0.f, qq = 0.f;
        #pragma unroll
        for (int st = 0; st < ST; ++st)
            #pragma unroll
            for (int j = 0; j < 4; ++j) {
                float v = acc[st][n][j];
                s += v; qq += v * v;
            }
        s4[n] = s; q4[n] = qq;
    }
    #pragma unroll
    for (int n = 0; n < 4; ++n) {
        s4[n] += __shfl_xor(s4[n], 16); s4[n] += __shfl_xor(s4[n], 32);
        q4[n] += __shfl_xor(q4[n], 16); q4[n] += __shfl_xor(q4[n], 32);
    }
    if (kgrp == 0) {
        #pragma unroll
        for (int n = 0; n < 4; ++n) {
            red[wv][0][n * 16 + colb] = s4[n];
            red[wv][1][n * 16 + colb] = q4[n];
        }
    }
    __syncthreads();
    if (tid < 64) {
        float S = 0.f, Q = 0.f;
        #pragma unroll
        for (int w8 = 0; w8 < 8; ++w8) { S += red[w8][0][tid]; Q += red[w8][1][tid]; }
        part[(size_t)wg * 128 + tid]      = S;
        part[(size_t)wg * 128 + 64 + tid] = Q;
    }
}

// ---------------------------------------------------------------------------
// FUSED: x = relu(bn(Yb)) -> xB   AND   projRaw = x @ wp -> prOut (+stats).
// 256 threads = 4 waves x 64 rows (ST=4) = 256 rows/block, grid 391.
// Eliminates the standalone proj conv (full xB re-read) and the down
// bn_apply pass. BN applied in-register between load and MFMA.
// ---------------------------------------------------------------------------
__global__ __launch_bounds__(256) void bn_proj_fused(
    const unsigned short* __restrict__ Yb,   // raw down out bf16 [M][64]
    const float* __restrict__ ss,            // down BN scale/shift
    const unsigned short* __restrict__ wpT,  // swizzled proj slab (64x64)
    unsigned short* __restrict__ xB,         // out: bn+relu bf16
    unsigned short* __restrict__ prOut,      // out: proj raw bf16
    float* __restrict__ part)
{
    constexpr int SLAB = 64 * 64;   // 4096 ushorts = 8KB

    __shared__ unsigned short Wl[SLAB];
    __shared__ float red[4][2][64];

    const int tid  = threadIdx.x;
    const int lane = tid & 63;
    const int wv   = tid >> 6;      // 0..3
    const int colb = lane & 15;
    const int kgrp = lane >> 4;

    const int nwg = gridDim.x;
    const int q   = nwg >> 3, r8 = nwg & 7;
    const int xcd = blockIdx.x & 7, pos = blockIdx.x >> 3;
    const int wg  = (xcd < r8 ? xcd * (q + 1) : r8 * (q + 1) + (xcd - r8) * q) + pos;
    const int m0  = wg * 256;

    // stage proj slab (2 x 16B per thread)
    #pragma unroll
    for (int r = 0; r < 2; ++r) {
        const void* gp = wpT + (size_t)(r * 256 + tid) * 8;
        void* lp = &Wl[(size_t)(r * 256 + wv * 64) * 8];
        gload_lds16(gp, lp);
    }

    // preload per-lane BN coefficients: channels kgrp*8 + s*32 + j
    float sc[2][8], sh[2][8];
    #pragma unroll
    for (int s = 0; s < 2; ++s) {
        int c0 = kgrp * 8 + s * 32;
        float4 A = *(const float4*)(ss + c0);
        float4 B = *(const float4*)(ss + c0 + 4);
        float4 C = *(const float4*)(ss + 64 + c0);
        float4 D = *(const float4*)(ss + 64 + c0 + 4);
        sc[s][0]=A.x; sc[s][1]=A.y; sc[s][2]=A.z; sc[s][3]=A.w;
        sc[s][4]=B.x; sc[s][5]=B.y; sc[s][6]=B.z; sc[s][7]=B.w;
        sh[s][0]=C.x; sh[s][1]=C.y; sh[s][2]=C.z; sh[s][3]=C.w;
        sh[s][4]=D.x; sh[s][5]=D.y; sh[s][6]=D.z; sh[s][7]=D.w;
    }
    __syncthreads();   // drains slab stage

    f32x4 acc[4][4] = {};

    #pragma unroll
    for (int st = 0; st < 4; ++st) {
        bf16x8 a[2];
        int row = m0 + wv * 64 + st * 16 + colb;
        if (row < M_ROWS) {
            const unsigned short* fp = Yb + (size_t)row * 64 + kgrp * 8;
            #pragma unroll
            for (int s = 0; s < 2; ++s) {
                u16x8 u = *reinterpret_cast<const u16x8*>(fp + s * 32);
                u16x8 o;
                #pragma unroll
                for (int j = 0; j < 8; ++j) {
                    float v = bf2f(u[j]) * sc[s][j] + sh[s][j];
                    v = fmaxf(v, 0.f);
                    o[j] = f2bf(v);
                }
                a[s] = __builtin_bit_cast(bf16x8, o);
                *reinterpret_cast<u16x8*>(xB + (size_t)row * 64 + kgrp * 8 + s * 32) = o;
            }
        } else {
            a[0] = bfzero(); a[1] = bfzero();
        }
        // proj MFMA (weights from LDS, XOR-swizzled, CIN=64)
        bf16x8 w[4][2];
        #pragma unroll
        for (int n = 0; n < 4; ++n) {
            int r  = n * 16 + colb;
            int xm = (r & 7) << 4;
            #pragma unroll
            for (int s = 0; s < 2; ++s) {
                int phys = r * 128 + ((kgrp * 16 + s * 64) ^ xm);
                w[n][s] = *reinterpret_cast<const bf16x8*>((const char*)&Wl[0] + phys);
            }
        }
        #pragma unroll
        for (int n = 0; n < 4; ++n)
            #pragma unroll
            for (int s = 0; s < 2; ++s)
                acc[st][n] = __builtin_amdgcn_mfma_f32_16x16x32_bf16(
                    a[s], w[n][s], acc[st][n], 0, 0, 0);
    }

    // proj raw write (bf16)
    #pragma unroll
    for (int st = 0; st < 4; ++st) {
        int rbase = m0 + wv * 64 + st * 16 + kgrp * 4;
        #pragma unroll
        for (int j = 0; j < 4; ++j) {
            int row = rbase + j;
            if (row < M_ROWS) {
                #pragma unroll
                for (int n = 0; n < 4; ++n)
                    prOut[(size_t)row * 64 + n * 16 + colb] = f2bf(acc[st][n][j]);
            }
        }
    }

    // fused proj BN partial stats
    float s4[4], q4[4];
    #pragma unroll
    for (int n = 0; n < 4; ++n) {
        float s = 0.f, qq = 0.f;
        #pragma unroll
        for (int st = 0; st < 4; ++st)
            #pragma unroll
            for (int j = 0; j < 4; ++j) {
                float v = acc[st][n][j];
                s += v; qq += v * v;
            }
        s4[n] = s; q4[n] = qq;
    }
    #pragma unroll
    for (int n = 0; n < 4; ++n) {
        s4[n] += __shfl_xor(s4[n], 16); s4[n] += __shfl_xor(s4[n], 32);
        q4[n] += __shfl_xor(q4[n], 16); q4[n] += __shfl_xor(q4[n], 32);
    }
    if (kgrp == 0) {
        #pragma unroll
        for (int n = 0; n < 4; ++n) {
            red[wv][0][n * 16 + colb] = s4[n];
            red[wv][1][n * 16 + colb] = q4[n];
        }
    }
    __syncthreads();
    if (tid < 64) {
        float S = red[0][0][tid] + red[1][0][tid] + red[2][0][tid] + red[3][0][tid];
        float Q = red[0][1][tid] + red[1][1][tid] + red[2][1][tid] + red[3][1][tid];
        part[(size_t)wg * 128 + tid]      = S;
        part[(size_t)wg * 128 + 64 + tid] = Q;
    }
}

// ---------------------------------------------------------------------------
// Reduce block partials -> per-channel scale/shift (1024 thr, 16 groups).
// ---------------------------------------------------------------------------
__global__ __launch_bounds__(1024) void bn_finalize(
    const float* __restrict__ part, int nblocks,
    const float* __restrict__ gg, const float* __restrict__ bb,
    float* __restrict__ ss, int M)
{
    const int tid = threadIdx.x;
    const int c   = tid & 63;
    const int grp = tid >> 6;
    float S = 0.f, Q = 0.f;
    int i = grp;
    for (; i + 48 < nblocks; i += 64) {
        float a0 = part[(size_t)(i     ) * 128 + c];
        float a1 = part[(size_t)(i + 16) * 128 + c];
        float a2 = part[(size_t)(i + 32) * 128 + c];
        float a3 = part[(size_t)(i + 48) * 128 + c];
        float q0 = part[(size_t)(i     ) * 128 + 64 + c];
        float q1 = part[(size_t)(i + 16) * 128 + 64 + c];
        float q2 = part[(size_t)(i + 32) * 128 + 64 + c];
        float q3 = part[(size_t)(i + 48) * 128 + 64 + c];
        S += a0 + a1 + a2 + a3;
        Q += q0 + q1 + q2 + q3;
    }
    for (; i < nblocks; i += 16) {
        S += part[(size_t)i * 128 + c];
        Q += part[(size_t)i * 128 + 64 + c];
    }
    __shared__ float sh[2][16][64];
    sh[0][grp][c] = S; sh[1][grp][c] = Q;
    __syncthreads();
    if (tid < 64) {
        float Sa = 0.f, Qa = 0.f;
        #pragma unroll
        for (int j = 0; j < 16; ++j) { Sa += sh[0][j][tid]; Qa += sh[1][j][tid]; }
        float mean = Sa / (float)M;
        float var  = Qa / (float)M - mean * mean;
        float rstd = rsqrtf(var + EPS);
        float sc = gg[tid] * rstd;
        ss[tid]      = sc;
        ss[64 + tid] = bb[tid] - mean * sc;
    }
}

// ---------------------------------------------------------------------------
// BN apply. INBF: bf16 input. BF16OUT: bf16 out. RELU.
// RES: add raw bf16 residual normalized on the fly with ssr (lazy proj BN).
// ---------------------------------------------------------------------------
template<bool INBF, bool BF16OUT, bool RES, bool RELU>
__global__ __launch_bounds__(256) void bn_apply(
    const void* __restrict__ yp, const float* __restrict__ ss,
    const unsigned short* __restrict__ res, const float* __restrict__ ssr,
    void* __restrict__ out, int n8)
{
    for (int i = blockIdx.x * 256 + threadIdx.x; i < n8; i += gridDim.x * 256) {
        float v[8];
        if (INBF) {
            u16x8 u = ((const u16x8*)yp)[i];
            #pragma unroll
            for (int j = 0; j < 8; ++j) v[j] = bf2f(u[j]);
        } else {
            float4 a = ((const float4*)yp)[2 * i];
            float4 b = ((const float4*)yp)[2 * i + 1];
            v[0] = a.x; v[1] = a.y; v[2] = a.z; v[3] = a.w;
            v[4] = b.x; v[5] = b.y; v[6] = b.z; v[7] = b.w;
        }
        int c0 = (i * 8) & 63;
        #pragma unroll
        for (int j = 0; j < 8; ++j)
            v[j] = v[j] * ss[c0 + j] + ss[64 + c0 + j];
        if (RES) {
            u16x8 rv = ((const u16x8*)res)[i];
            #pragma unroll
            for (int j = 0; j < 8; ++j)
                v[j] += bf2f(rv[j]) * ssr[c0 + j] + ssr[64 + c0 + j];
        }
        if (RELU) {
            #pragma unroll
            for (int j = 0; j < 8; ++j) v[j] = fmaxf(v[j], 0.f);
        }
        if (BF16OUT) {
            u16x8 o;
            #pragma unroll
            for (int j = 0; j < 8; ++j) o[j] = f2bf(v[j]);
            ((u16x8*)out)[i] = o;
        } else {
            float4 oa, ob;
            oa.x = v[0]; oa.y = v[1]; oa.z = v[2]; oa.w = v[3];
            ob.x = v[4]; ob.y = v[5]; ob.z = v[6]; ob.w = v[7];
            ((float4*)out)[2 * i]     = oa;
            ((float4*)out)[2 * i + 1] = ob;
        }
    }
}

// ---------------------------------------------------------------------------
extern "C" void kernel_launch(void* const* d_in, const int* in_sizes, int n_in,
                              void* d_out, int out_size, void* d_ws, size_t ws_size,
                              hipStream_t stream)
{
    const float* x_feats = (const float*)d_in[0];
    const float* w_down  = (const float*)d_in[1];
    const float* g_down  = (const float*)d_in[2];
    const float* b_down  = (const float*)d_in[3];
    const float* w_proj  = (const float*)d_in[4];
    const float* g_p     = (const float*)d_in[5];
    const float* b_p     = (const float*)d_in[6];
    const float* w1      = (const float*)d_in[7];
    const float* g1      = (const float*)d_in[8];
    const float* b1      = (const float*)d_in[9];
    const float* w2      = (const float*)d_in[10];
    const float* g2      = (const float*)d_in[11];
    const float* b2      = (const float*)d_in[12];
    const int*   nbr_down = (const int*)d_in[13];
    const int*   nbr_sub  = (const int*)d_in[14];
    float* out = (float*)d_out;

    const int M = M_ROWS;
    const int conv_grid = (M + 255) / 256;       // 391
    const size_t feat2 = (size_t)(M + 1) * CO * 2;
    auto align = [](size_t x) { return (x + 255) & ~(size_t)255; };

    char* ws = (char*)d_ws;
    size_t off = 0;
    unsigned short* xin16 = (unsigned short*)(ws + off); off += align((size_t)(N_IN + 1) * C_IN * 2);
    unsigned short* wdT   = (unsigned short*)(ws + off); off += align((size_t)8 * CO * C_IN * 2);
    unsigned short* wpT   = (unsigned short*)(ws + off); off += align((size_t)1 * CO * CO * 2);
    unsigned short* w1T   = (unsigned short*)(ws + off); off += align((size_t)27 * CO * CO * 2);
    unsigned short* w2T   = (unsigned short*)(ws + off); off += align((size_t)27 * CO * CO * 2);
    unsigned short* Yb    = (unsigned short*)(ws + off); off += align(feat2);  // raw conv out
    unsigned short* bufRb = (unsigned short*)(ws + off); off += align(feat2);  // proj RAW bf16
    unsigned short* xB    = (unsigned short*)(ws + off); off += align(feat2);
    unsigned short* zB    = (unsigned short*)(ws + off); off += align(feat2);
    float* part = (float*)(ws + off); off += align((size_t)1024 * 128 * 4);
    float* ss0  = (float*)(ws + off);
    float* ss1  = ss0 + 128;
    float* ss2  = ss1 + 128;
    float* ss3  = ss2 + 128;

    const int n8 = M * CO / 8;
    const int ew_grid = 2048;

    // zero dummy rows (idx<0 gathers land here)
    hipMemsetAsync(xin16 + (size_t)N_IN * C_IN, 0, C_IN * 2, stream);
    hipMemsetAsync(xB + (size_t)M * CO, 0, CO * 2, stream);
    hipMemsetAsync(zB + (size_t)M * CO, 0, CO * 2, stream);

    // 0) input cast + ALL weight casts
    {
        int nf8 = N_IN * C_IN / 8;
        cvt_bf16<<<(nf8 + 255) / 256, 256, 0, stream>>>(x_feats, xin16, nf8);
        wt_cvt_all<<<(241664 + 255) / 256, 256, 0, stream>>>(
            w_down, w_proj, w1, w2, wdT, wpT, w1T, w2T);
    }

    // 1) down conv -> Yb bf16 (+stats); finalize ss0
    spconv_mfma<C_IN, 8, true, true><<<conv_grid, 512, 0, stream>>>(
        xin16, N_IN, nbr_down, wdT, Yb, part);
    bn_finalize<<<1, 1024, 0, stream>>>(part, conv_grid, g_down, b_down, ss0, M);

    // 2) FUSED: x = relu(bn(Yb)) -> xB ; projRaw = x @ wp -> bufRb (+stats)
    bn_proj_fused<<<conv_grid, 256, 0, stream>>>(Yb, ss0, wpT, xB, bufRb, part);
    bn_finalize<<<1, 1024, 0, stream>>>(part, conv_grid, g_p, b_p, ss1, M);

    // 3) conv1: Yb = raw spconv(x, nbr_sub, w1) (+stats); z = relu(bn) -> zB
    spconv_mfma<CO, 27, true, true><<<conv_grid, 512, 0, stream>>>(
        xB, M, nbr_sub, w1T, Yb, part);
    bn_finalize<<<1, 1024, 0, stream>>>(part, conv_grid, g1, b1, ss2, M);
    bn_apply<true, true, false, true><<<ew_grid, 256, 0, stream>>>(
        Yb, ss2, nullptr, nullptr, zB, n8);

    // 4) conv2 (+stats); out = relu(bn2(raw) + bn_p(projRaw))  [lazy proj BN]
    spconv_mfma<CO, 27, true, true><<<conv_grid, 512, 0, stream>>>(
        zB, M, nbr_sub, w2T, Yb, part);
    bn_finalize<<<1, 1024, 0, stream>>>(part, conv_grid, g2, b2, ss3, M);
    bn_apply<true, false, true, true><<<ew_grid, 256, 0, stream>>>(
        Yb, ss3, bufRb, ss1, out, n8);
}